// Round 2
// baseline (614.809 us; speedup 1.0000x reference)
//
#include <hip/hip_runtime.h>

#define S_LEN 512
#define BATCH 256
#define EMB   300
#define HID   256

typedef __attribute__((ext_vector_type(8))) _Float16 f16x8;
typedef __attribute__((ext_vector_type(4))) _Float16 f16x4;
typedef __attribute__((ext_vector_type(4))) float    f32x4;

// Barrier that waits only lgkmcnt(0) (LDS ordering) and leaves global loads in
// flight (vmcnt untouched) -> register prefetch survives the barrier.
// imm: vmcnt=63 (bits[3:0]=0xF,[15:14]=3), expcnt=7 ([6:4]), lgkmcnt=0 ([11:8]).
__device__ __forceinline__ void block_sync_lds() {
    asm volatile("" ::: "memory");
    __builtin_amdgcn_s_waitcnt(0xC07F);
    __builtin_amdgcn_s_barrier();
    asm volatile("" ::: "memory");
}

__device__ __forceinline__ float sigmoidf_fast(float x) {
    float e = __builtin_amdgcn_exp2f(x * -1.44269504089f);   // e^{-x}
    return __builtin_amdgcn_rcpf(1.0f + e);                  // inf -> 0, correct limit
}

// ---------------------------------------------------------------------------
// Kernel A: A_ws[t][b][j] = (emb[words[b,t]] @ Wi)[j]  as fp16.
// Block tile: 64 rows (m = t*256+b) x 256 cols; 4 waves split N (64 cols each).
// Wi fragments (fp32 -> fp16) preloaded to registers; gathered emb rows staged
// fp32->fp16 through LDS per 32-wide K chunk, prefetch kept in flight across
// the lgkm-only barrier.
// ---------------------------------------------------------------------------
#define ASTR 40   // LDS A-tile stride in elements (80 B, 16B-aligned rows)

__global__ __launch_bounds__(256, 1)
void k_embed_gemm(const int* __restrict__ words, const float* __restrict__ emb,
                  const float* __restrict__ Wi, _Float16* __restrict__ Aws) {
    __shared__ __attribute__((aligned(16))) _Float16 lds_a[64 * ASTR];

    const int tid  = threadIdx.x;
    const int wv   = tid >> 6;        // wave 0..3 (N-split)
    const int lane = tid & 63;
    const int ln   = lane & 15;
    const int q    = lane >> 4;
    const int m0   = blockIdx.x * 64;

    // ---- preload Wi fragments: B[k][n], k = kc*32 + q*8 + j, n = wv*64 + nt*16 + ln
    f16x8 bfrag[10][4];
#pragma unroll
    for (int kc = 0; kc < 10; kc++) {
#pragma unroll
        for (int nt = 0; nt < 4; nt++) {
            const int n = wv * 64 + nt * 16 + ln;
            f16x8 u;
#pragma unroll
            for (int j = 0; j < 8; j++) {
                const int k = kc * 32 + q * 8 + j;
                u[j] = (k < EMB) ? (_Float16)Wi[k * HID + n] : (_Float16)0.f;
            }
            bfrag[kc][nt] = u;
        }
    }

    f32x4 acc[4][4];
#pragma unroll
    for (int mt = 0; mt < 4; mt++)
#pragma unroll
        for (int nt = 0; nt < 4; nt++)
            acc[mt][nt] = f32x4{0.f, 0.f, 0.f, 0.f};

    // staging role: thread t covers row (t>>2), k-segment (t&3) (8 fp32 -> 8 fp16)
    const int srow = tid >> 2, sseg = tid & 3;
    const int m    = m0 + srow;
    const int tseq = m >> 8, bb = m & 255;
    const float* arow = emb + (long)words[bb * S_LEN + tseq] * EMB;

    auto load_chunk = [&](int kc) -> f16x8 {
        const int k0 = kc * 32 + sseg * 8;
        f16x8 v;
        if (k0 + 8 <= EMB) {
            f32x4 a = *(const f32x4*)(arow + k0);      // emb rows are 16B-aligned (1200 B stride)
            f32x4 b = *(const f32x4*)(arow + k0 + 4);
#pragma unroll
            for (int r = 0; r < 4; r++) { v[r] = (_Float16)a[r]; v[4 + r] = (_Float16)b[r]; }
        } else {
#pragma unroll
            for (int j = 0; j < 8; j++)
                v[j] = (k0 + j < EMB) ? (_Float16)arow[k0 + j] : (_Float16)0.f;
        }
        return v;
    };

    f16x8 av = load_chunk(0);
#pragma unroll
    for (int kc = 0; kc < 10; kc++) {
        *(f16x8*)&lds_a[srow * ASTR + sseg * 8] = av;
        block_sync_lds();
        if (kc < 9) av = load_chunk(kc + 1);       // prefetch, stays in flight
        f16x8 af[4];
#pragma unroll
        for (int mt = 0; mt < 4; mt++)
            af[mt] = *(const f16x8*)&lds_a[(mt * 16 + ln) * ASTR + q * 8];
#pragma unroll
        for (int mt = 0; mt < 4; mt++)
#pragma unroll
            for (int nt = 0; nt < 4; nt++)
                acc[mt][nt] = __builtin_amdgcn_mfma_f32_16x16x32_f16(
                    af[mt], bfrag[kc][nt], acc[mt][nt], 0, 0, 0);
        block_sync_lds();
    }

    // epilogue: C row = m0 + mt*16 + q*4 + r, col = wv*64 + nt*16 + ln
#pragma unroll
    for (int mt = 0; mt < 4; mt++)
#pragma unroll
        for (int nt = 0; nt < 4; nt++) {
            const int col = wv * 64 + nt * 16 + ln;
#pragma unroll
            for (int r = 0; r < 4; r++) {
                const int mm = m0 + mt * 16 + q * 4 + r;
                Aws[(long)mm * HID + col] = (_Float16)acc[mt][nt][r];
            }
        }
}

// ---------------------------------------------------------------------------
// Kernel B: recurrence. 16 blocks x 16 batch rows, 256 threads (4 waves).
// Computes C'[j][b] = sum_k Wh[k][j] * h[b][k] (transposed product) so h_new
// LDS writes are vectorizable. Wh^T fp16 fragments live in registers (waves
// split j); h ping-pongs between two fp16 LDS buffers -> one lgkm-only
// barrier per step; a_t register-prefetched 2 steps ahead.
// ---------------------------------------------------------------------------
#define HSTR 272            // h buffer stride in elements (544 B, 16B-aligned)
#define HB   (16 * HSTR)

__global__ __launch_bounds__(256, 1)
void k_recur(const float* __restrict__ Wh, const _Float16* __restrict__ Aws,
             const float* __restrict__ fcw, const float* __restrict__ fcb,
             float* __restrict__ out) {
    __shared__ __attribute__((aligned(16))) _Float16 hbuf[2 * HB];
    __shared__ float red[256];

    const int tid  = threadIdx.x;
    const int wv   = tid >> 6;
    const int lane = tid & 63;
    const int ln   = lane & 15;
    const int q    = lane >> 4;
    const int b0   = blockIdx.x * 16;

    // ---- preload Wh^T fragments: A'[m=j][k] = Wh[k][j], j = wv*64 + mt*16 + ln
    f16x8 whf[8][4];
#pragma unroll
    for (int kc = 0; kc < 8; kc++) {
#pragma unroll
        for (int mt = 0; mt < 4; mt++) {
            const int j = wv * 64 + mt * 16 + ln;
            f16x8 u;
#pragma unroll
            for (int jj = 0; jj < 8; jj++)
                u[jj] = (_Float16)Wh[(kc * 32 + q * 8 + jj) * HID + j];
            whf[kc][mt] = u;
        }
    }

    // zero both h buffers (h0 = 0)
    for (int i = tid; i < 2 * HB; i += 256) hbuf[i] = (_Float16)0.f;
    __syncthreads();

    // a_t prefetch: lane reads b = b0+ln, j = wv*64 + mt*16 + q*4 + {0..3}
    const _Float16* abase = Aws + (long)(b0 + ln) * HID + wv * 64 + q * 4;
    f16x4 abuf0[4], abuf1[4];
#pragma unroll
    for (int mt = 0; mt < 4; mt++) abuf0[mt] = *(const f16x4*)(abase + 0L * 65536 + mt * 16);
#pragma unroll
    for (int mt = 0; mt < 4; mt++) abuf1[mt] = *(const f16x4*)(abase + 1L * 65536 + mt * 16);

#define STEP(T, ABUF)                                                                   \
    {                                                                                   \
        const int tt = (T);                                                             \
        const _Float16* hr = hbuf + ((tt & 1) ? HB : 0);                                \
        _Float16*       hw = hbuf + ((tt & 1) ? 0 : HB);                                \
        f16x8 hf[8];                                                                    \
        _Pragma("unroll")                                                               \
        for (int kc = 0; kc < 8; kc++)                                                  \
            hf[kc] = *(const f16x8*)(hr + ln * HSTR + kc * 32 + q * 8);                 \
        f32x4 acc[4];                                                                   \
        _Pragma("unroll")                                                               \
        for (int mt = 0; mt < 4; mt++) acc[mt] = f32x4{0.f, 0.f, 0.f, 0.f};             \
        _Pragma("unroll")                                                               \
        for (int kc = 0; kc < 8; kc++) {                                                \
            _Pragma("unroll")                                                           \
            for (int mt = 0; mt < 4; mt++)                                              \
                acc[mt] = __builtin_amdgcn_mfma_f32_16x16x32_f16(                       \
                    whf[kc][mt], hf[kc], acc[mt], 0, 0, 0);                             \
        }                                                                               \
        const long toff = (long)((tt + 2 > 511) ? 511 : (tt + 2)) * 65536;              \
        _Pragma("unroll")                                                               \
        for (int mt = 0; mt < 4; mt++) {                                                \
            f16x4 av = ABUF[mt];                                                        \
            ABUF[mt] = *(const f16x4*)(abase + toff + mt * 16);                         \
            f16x4 hp;                                                                   \
            _Pragma("unroll")                                                           \
            for (int r = 0; r < 4; r++) {                                               \
                float x  = acc[mt][r] + (float)av[r];                                   \
                hp[r] = (_Float16)sigmoidf_fast(x);                                     \
            }                                                                           \
            *(f16x4*)(hw + ln * HSTR + wv * 64 + mt * 16 + q * 4) = hp;                 \
        }                                                                               \
        block_sync_lds();                                                               \
    }

    for (int t = 0; t < S_LEN; t += 2) {
        STEP(t, abuf0);
        STEP(t + 1, abuf1);
    }
#undef STEP

    // step 511 (odd) wrote buffer 0 -> final h lives there
    const _Float16* hf0 = hbuf;

    // hidden -> out[256 + (b0+row)*256 + j]  (fp32)
    {
        const int row = tid >> 4, j0 = (tid & 15) * 16;
        float* dst = out + 256 + (long)(b0 + row) * HID + j0;
#pragma unroll
        for (int v = 0; v < 16; v += 4) {
            f32x4 w;
#pragma unroll
            for (int r = 0; r < 4; r++) w[r] = (float)hf0[row * HSTR + j0 + v + r];
            *(f32x4*)(dst + v) = w;
        }
    }

    // sig = sigmoid(h @ fc_w + fc_b) for this block's 16 rows
    {
        const int bl = tid >> 4, part = tid & 15;
        float s = 0.f;
#pragma unroll
        for (int jj = 0; jj < 16; jj++) {
            const int j = part * 16 + jj;
            s += (float)hf0[bl * HSTR + j] * fcw[j];
        }
        red[bl * 16 + part] = s;
    }
    __syncthreads();
    if (tid < 16) {
        float s = fcb[0];
#pragma unroll
        for (int p = 0; p < 16; p++) s += red[tid * 16 + p];
        out[b0 + tid] = sigmoidf_fast(s);
    }
}

extern "C" void kernel_launch(void* const* d_in, const int* in_sizes, int n_in,
                              void* d_out, int out_size, void* d_ws, size_t ws_size,
                              hipStream_t stream) {
    const int*   words = (const int*)d_in[0];
    const float* emb   = (const float*)d_in[1];
    const float* Wi    = (const float*)d_in[2];
    const float* Wh    = (const float*)d_in[3];
    const float* fcw   = (const float*)d_in[4];
    const float* fcb   = (const float*)d_in[5];
    _Float16* Aws  = (_Float16*)d_ws;                 // [512][256][256] fp16 = 64 MiB
    float*    outp = (float*)d_out;

    hipLaunchKernelGGL(k_embed_gemm, dim3((S_LEN * BATCH) / 64), dim3(256), 0, stream,
                       words, emb, Wi, Aws);
    hipLaunchKernelGGL(k_recur, dim3(BATCH / 16), dim3(256), 0, stream,
                       Wh, Aws, fcw, fcb, outp);
}

// Round 3
// 560.285 us; speedup vs baseline: 1.0973x; 1.0973x over previous
//
#include <hip/hip_runtime.h>

#define S_LEN 512
#define BATCH 256
#define EMB   300
#define HID   256

typedef __attribute__((ext_vector_type(8))) _Float16 f16x8;
typedef __attribute__((ext_vector_type(4))) _Float16 f16x4;
typedef __attribute__((ext_vector_type(4))) float    f32x4;

// Barrier that waits only lgkmcnt(0) (LDS ordering) and leaves global loads in
// flight (vmcnt untouched) -> register prefetch survives the barrier.
// imm: vmcnt=63 (bits[3:0]=0xF,[15:14]=3), expcnt=7 ([6:4]), lgkmcnt=0 ([11:8]).
__device__ __forceinline__ void block_sync_lds() {
    asm volatile("" ::: "memory");
    __builtin_amdgcn_s_waitcnt(0xC07F);
    __builtin_amdgcn_s_barrier();
    asm volatile("" ::: "memory");
}

__device__ __forceinline__ float sigmoidf_fast(float x) {
    float e = __builtin_amdgcn_exp2f(x * -1.44269504089f);   // e^{-x}
    return __builtin_amdgcn_rcpf(1.0f + e);                  // inf -> 0, correct limit
}

__device__ __forceinline__ void wait_group(unsigned int* cnt, int g) {
    // uniform spin; producers post 32 increments per 8-t group
    while (__hip_atomic_load(&cnt[g], __ATOMIC_ACQUIRE, __HIP_MEMORY_SCOPE_AGENT) < 32u)
        __builtin_amdgcn_s_sleep(2);
}

// ---------------------------------------------------------------------------
// Producer: A_ws[t][b][j] = (emb[words[b,t]] @ Wi)[j] as fp16.
// Block = 64 rows (m = t*256+b) x 256 cols; 4 waves split N. pp covers one t
// quarter (64 rows within a single t). In FUSED mode, posts to cnt[t>>3].
// ---------------------------------------------------------------------------
#define ASTR 40   // LDS A-tile stride in elems (80 B; 20 dwords -> 4*odd mod 32, conflict-free)

template<bool FUSED>
__device__ void producer_body(int pp, const int* __restrict__ words,
                              const float* __restrict__ emb, const float* __restrict__ Wi,
                              _Float16* __restrict__ Aws, unsigned int* cnt) {
    __shared__ __attribute__((aligned(16))) _Float16 lds_a[64 * ASTR];

    const int tid  = threadIdx.x;
    const int wv   = tid >> 6;
    const int lane = tid & 63;
    const int ln   = lane & 15;
    const int q    = lane >> 4;
    const int m0   = pp * 64;

    // preload Wi fragments: B[k][n], k = kc*32 + q*8 + j, n = wv*64 + nt*16 + ln
    f16x8 bfrag[10][4];
#pragma unroll
    for (int kc = 0; kc < 10; kc++) {
#pragma unroll
        for (int nt = 0; nt < 4; nt++) {
            const int n = wv * 64 + nt * 16 + ln;
            f16x8 u;
#pragma unroll
            for (int j = 0; j < 8; j++) {
                const int k = kc * 32 + q * 8 + j;
                u[j] = (k < EMB) ? (_Float16)Wi[k * HID + n] : (_Float16)0.f;
            }
            bfrag[kc][nt] = u;
        }
    }

    f32x4 acc[4][4];
#pragma unroll
    for (int mt = 0; mt < 4; mt++)
#pragma unroll
        for (int nt = 0; nt < 4; nt++)
            acc[mt][nt] = f32x4{0.f, 0.f, 0.f, 0.f};

    const int srow = tid >> 2, sseg = tid & 3;
    const int m    = m0 + srow;
    const int tseq = m >> 8, bb = m & 255;
    const float* arow = emb + (long)words[bb * S_LEN + tseq] * EMB;

    auto load_chunk = [&](int kc) -> f16x8 {
        const int k0 = kc * 32 + sseg * 8;
        f16x8 v;
        if (k0 + 8 <= EMB) {
            f32x4 a = *(const f32x4*)(arow + k0);
            f32x4 b = *(const f32x4*)(arow + k0 + 4);
#pragma unroll
            for (int r = 0; r < 4; r++) { v[r] = (_Float16)a[r]; v[4 + r] = (_Float16)b[r]; }
        } else {
#pragma unroll
            for (int j = 0; j < 8; j++)
                v[j] = (k0 + j < EMB) ? (_Float16)arow[k0 + j] : (_Float16)0.f;
        }
        return v;
    };

    f16x8 av = load_chunk(0);
#pragma unroll
    for (int kc = 0; kc < 10; kc++) {
        *(f16x8*)&lds_a[srow * ASTR + sseg * 8] = av;
        block_sync_lds();
        if (kc < 9) av = load_chunk(kc + 1);
        f16x8 af[4];
#pragma unroll
        for (int mt = 0; mt < 4; mt++)
            af[mt] = *(const f16x8*)&lds_a[(mt * 16 + ln) * ASTR + q * 8];
#pragma unroll
        for (int mt = 0; mt < 4; mt++)
#pragma unroll
            for (int nt = 0; nt < 4; nt++)
                acc[mt][nt] = __builtin_amdgcn_mfma_f32_16x16x32_f16(
                    af[mt], bfrag[kc][nt], acc[mt][nt], 0, 0, 0);
        block_sync_lds();
    }

#pragma unroll
    for (int mt = 0; mt < 4; mt++)
#pragma unroll
        for (int nt = 0; nt < 4; nt++) {
            const int col = wv * 64 + nt * 16 + ln;
#pragma unroll
            for (int r = 0; r < 4; r++) {
                const int mm = m0 + mt * 16 + q * 4 + r;
                Aws[(long)mm * HID + col] = (_Float16)acc[mt][nt][r];
            }
        }

    if (FUSED) {
        __syncthreads();                 // drains vmcnt(0): all block stores complete
        if (tid == 0) {
            __threadfence();             // agent-scope release of the A stores
            __hip_atomic_fetch_add(&cnt[pp >> 5], 1u,
                                   __ATOMIC_RELEASE, __HIP_MEMORY_SCOPE_AGENT);
        }
    }
}

// ---------------------------------------------------------------------------
// Consumer: recurrence. 16 blocks x 16 batch rows, 4 waves (waves split j).
// HSTR = 264 elems = 132 dwords; 132 mod 32 = 4 -> 8 consecutive lanes hit 8
// distinct 4-dword bank windows: conflict-free b128 reads, 2-way (free) writes.
// ---------------------------------------------------------------------------
#define HSTR 264
#define HB   (16 * HSTR)

template<bool FUSED>
__device__ void consumer_body(const float* __restrict__ Wh, const _Float16* __restrict__ Aws,
                              const float* __restrict__ fcw, const float* __restrict__ fcb,
                              float* __restrict__ out, unsigned int* cnt) {
    __shared__ __attribute__((aligned(16))) _Float16 hbuf[2 * HB];
    __shared__ float red[256];

    const int tid  = threadIdx.x;
    const int wv   = tid >> 6;
    const int lane = tid & 63;
    const int ln   = lane & 15;
    const int q    = lane >> 4;
    const int b0   = blockIdx.x * 16;

    // preload Wh^T fragments: A'[m=j][k] = Wh[k][j], j = wv*64 + mt*16 + ln
    f16x8 whf[8][4];
#pragma unroll
    for (int kc = 0; kc < 8; kc++) {
#pragma unroll
        for (int mt = 0; mt < 4; mt++) {
            const int j = wv * 64 + mt * 16 + ln;
            f16x8 u;
#pragma unroll
            for (int jj = 0; jj < 8; jj++)
                u[jj] = (_Float16)Wh[(kc * 32 + q * 8 + jj) * HID + j];
            whf[kc][mt] = u;
        }
    }

    for (int i = tid; i < 2 * HB; i += 256) hbuf[i] = (_Float16)0.f;
    __syncthreads();

    if (FUSED) wait_group(cnt, 0);     // covers initial prefetch t=0,1 (and t<=7)

    const _Float16* abase = Aws + (long)(b0 + ln) * HID + wv * 64 + q * 4;
    f16x4 abuf0[4], abuf1[4];
#pragma unroll
    for (int mt = 0; mt < 4; mt++) abuf0[mt] = *(const f16x4*)(abase + 0L * 65536 + mt * 16);
#pragma unroll
    for (int mt = 0; mt < 4; mt++) abuf1[mt] = *(const f16x4*)(abase + 1L * 65536 + mt * 16);

#define STEP(T, ABUF)                                                                   \
    {                                                                                   \
        const int tt = (T);                                                             \
        const _Float16* hr = hbuf + ((tt & 1) ? HB : 0);                                \
        _Float16*       hw = hbuf + ((tt & 1) ? 0 : HB);                                \
        f16x8 hf[8];                                                                    \
        _Pragma("unroll")                                                               \
        for (int kc = 0; kc < 8; kc++)                                                  \
            hf[kc] = *(const f16x8*)(hr + ln * HSTR + kc * 32 + q * 8);                 \
        f32x4 acc[4];                                                                   \
        _Pragma("unroll")                                                               \
        for (int mt = 0; mt < 4; mt++) acc[mt] = f32x4{0.f, 0.f, 0.f, 0.f};             \
        _Pragma("unroll")                                                               \
        for (int kc = 0; kc < 8; kc++) {                                                \
            _Pragma("unroll")                                                           \
            for (int mt = 0; mt < 4; mt++)                                              \
                acc[mt] = __builtin_amdgcn_mfma_f32_16x16x32_f16(                       \
                    whf[kc][mt], hf[kc], acc[mt], 0, 0, 0);                             \
        }                                                                               \
        const long toff = (long)((tt + 2 > 511) ? 511 : (tt + 2)) * 65536;              \
        _Pragma("unroll")                                                               \
        for (int mt = 0; mt < 4; mt++) {                                                \
            f16x4 av = ABUF[mt];                                                        \
            ABUF[mt] = *(const f16x4*)(abase + toff + mt * 16);                         \
            f16x4 hp;                                                                   \
            _Pragma("unroll")                                                           \
            for (int r = 0; r < 4; r++) {                                               \
                float x  = acc[mt][r] + (float)av[r];                                   \
                hp[r] = (_Float16)sigmoidf_fast(x);                                     \
            }                                                                           \
            *(f16x4*)(hw + ln * HSTR + wv * 64 + mt * 16 + q * 4) = hp;                 \
        }                                                                               \
        block_sync_lds();                                                               \
    }

    for (int g = 0; g < 64; g++) {
        if (FUSED) wait_group(cnt, (g + 1 > 63) ? 63 : g + 1);  // covers prefetch t<=8g+9
        const int t0 = g * 8;
#pragma unroll
        for (int u = 0; u < 8; u += 2) {
            STEP(t0 + u,     abuf0);
            STEP(t0 + u + 1, abuf1);
        }
    }
#undef STEP

    const _Float16* hf0 = hbuf;   // step 511 (odd) wrote buffer 0

    {
        const int row = tid >> 4, j0 = (tid & 15) * 16;
        float* dst = out + 256 + (long)(b0 + row) * HID + j0;
#pragma unroll
        for (int v = 0; v < 16; v += 4) {
            f32x4 w;
#pragma unroll
            for (int r = 0; r < 4; r++) w[r] = (float)hf0[row * HSTR + j0 + v + r];
            *(f32x4*)(dst + v) = w;
        }
    }

    {
        const int bl = tid >> 4, part = tid & 15;
        float s = 0.f;
#pragma unroll
        for (int jj = 0; jj < 16; jj++) {
            const int j = part * 16 + jj;
            s += (float)hf0[bl * HSTR + j] * fcw[j];
        }
        red[bl * 16 + part] = s;
    }
    __syncthreads();
    if (tid < 16) {
        float s = fcb[0];
#pragma unroll
        for (int p = 0; p < 16; p++) s += red[tid * 16 + p];
        out[b0 + tid] = sigmoidf_fast(s);
    }
}

// ---------------------------------------------------------------------------
__global__ __launch_bounds__(256, 1)
void k_fused(const int* __restrict__ words, const float* __restrict__ emb,
             const float* __restrict__ Wi, const float* __restrict__ Wh,
             const float* __restrict__ fcw, const float* __restrict__ fcb,
             _Float16* __restrict__ Aws, unsigned int* cnt, float* __restrict__ out) {
    if (blockIdx.x < 16) consumer_body<true>(Wh, Aws, fcw, fcb, out, cnt);
    else                 producer_body<true>(blockIdx.x - 16, words, emb, Wi, Aws, cnt);
}

__global__ __launch_bounds__(256, 1)
void k_prod(const int* __restrict__ words, const float* __restrict__ emb,
            const float* __restrict__ Wi, _Float16* __restrict__ Aws) {
    producer_body<false>(blockIdx.x, words, emb, Wi, Aws, nullptr);
}

__global__ __launch_bounds__(256, 1)
void k_cons(const float* __restrict__ Wh, const _Float16* __restrict__ Aws,
            const float* __restrict__ fcw, const float* __restrict__ fcb,
            float* __restrict__ out) {
    consumer_body<false>(Wh, Aws, fcw, fcb, out, nullptr);
}

__global__ void k_init(unsigned int* cnt) {
    if (threadIdx.x < 64) cnt[threadIdx.x] = 0u;
}

extern "C" void kernel_launch(void* const* d_in, const int* in_sizes, int n_in,
                              void* d_out, int out_size, void* d_ws, size_t ws_size,
                              hipStream_t stream) {
    const int*   words = (const int*)d_in[0];
    const float* emb   = (const float*)d_in[1];
    const float* Wi    = (const float*)d_in[2];
    const float* Wh    = (const float*)d_in[3];
    const float* fcw   = (const float*)d_in[4];
    const float* fcb   = (const float*)d_in[5];
    _Float16*     Aws  = (_Float16*)d_ws;                       // 64 MiB
    unsigned int* cnt  = (unsigned int*)((char*)d_ws + 67108864);
    float*        outp = (float*)d_out;

    if (ws_size >= 67108864ull + 256ull) {
        hipLaunchKernelGGL(k_init, dim3(1), dim3(64), 0, stream, cnt);
        hipLaunchKernelGGL(k_fused, dim3(16 + 2048), dim3(256), 0, stream,
                           words, emb, Wi, Wh, fcw, fcb, Aws, cnt, outp);
    } else {
        hipLaunchKernelGGL(k_prod, dim3(2048), dim3(256), 0, stream, words, emb, Wi, Aws);
        hipLaunchKernelGGL(k_cons, dim3(16), dim3(256), 0, stream, Wh, Aws, fcw, fcb, outp);
    }
}

// Round 4
// 534.942 us; speedup vs baseline: 1.1493x; 1.0474x over previous
//
#include <hip/hip_runtime.h>

#define S_LEN 512
#define BATCH 256
#define EMB   300
#define HID   256
#define VOCAB 50257
#define NPROD 786                       // ceil(50257/64)
#define EMBWI_BYTES 51463168ull        // 50257*256*4

typedef __attribute__((ext_vector_type(8))) _Float16 f16x8;
typedef __attribute__((ext_vector_type(4))) _Float16 f16x4;
typedef __attribute__((ext_vector_type(4))) float    f32x4;

// Barrier that waits only lgkmcnt(0): LDS ordering preserved, global loads
// stay in flight across it (vmcnt untouched).
__device__ __forceinline__ void block_sync_lds() {
    asm volatile("" ::: "memory");
    __builtin_amdgcn_s_waitcnt(0xC07F);   // vmcnt=63, expcnt=7, lgkmcnt=0
    __builtin_amdgcn_s_barrier();
    asm volatile("" ::: "memory");
}

__device__ __forceinline__ float sigmoidf_fast(float x) {
    float e = __builtin_amdgcn_exp2f(x * -1.44269504089f);
    return __builtin_amdgcn_rcpf(1.0f + e);
}

// ---------------------------------------------------------------------------
// Producer: EmbWi[v][j] = (emb[v] @ Wi)[j], f32.  786 blocks x 64 rows.
// Contiguous rows -> fully coalesced staging; Wi fp16 fragments in registers.
// ---------------------------------------------------------------------------
#define ASTR 40   // LDS stride 80 B: conflict-free b128 reads (20 dwords, 20%32=4-odd)

__device__ void producer_body(int pp, const float* __restrict__ emb,
                              const float* __restrict__ Wi, float* __restrict__ EW,
                              unsigned int* cnt) {
    __shared__ __attribute__((aligned(16))) _Float16 lds_a[64 * ASTR];

    const int tid  = threadIdx.x;
    const int wv   = tid >> 6;
    const int lane = tid & 63;
    const int ln   = lane & 15;
    const int q    = lane >> 4;
    const int m0   = pp * 64;

    // Wi fragments: B[k][n], k = kc*32 + q*8 + j, n = wv*64 + nt*16 + ln
    f16x8 bfrag[10][4];
#pragma unroll
    for (int kc = 0; kc < 10; kc++) {
#pragma unroll
        for (int nt = 0; nt < 4; nt++) {
            const int n = wv * 64 + nt * 16 + ln;
            f16x8 u;
#pragma unroll
            for (int j = 0; j < 8; j++) {
                const int k = kc * 32 + q * 8 + j;
                u[j] = (k < EMB) ? (_Float16)Wi[k * HID + n] : (_Float16)0.f;
            }
            bfrag[kc][nt] = u;
        }
    }

    f32x4 acc[4][4];
#pragma unroll
    for (int mt = 0; mt < 4; mt++)
#pragma unroll
        for (int nt = 0; nt < 4; nt++)
            acc[mt][nt] = f32x4{0.f, 0.f, 0.f, 0.f};

    const int srow = tid >> 2, sseg = tid & 3;
    int row = m0 + srow; if (row >= VOCAB) row = VOCAB - 1;
    const float* arow = emb + (long)row * EMB;

    auto load_chunk = [&](int kc) -> f16x8 {
        const int k0 = kc * 32 + sseg * 8;
        f16x8 v;
        if (k0 + 8 <= EMB) {
            f32x4 a = *(const f32x4*)(arow + k0);
            f32x4 b = *(const f32x4*)(arow + k0 + 4);
#pragma unroll
            for (int r = 0; r < 4; r++) { v[r] = (_Float16)a[r]; v[4 + r] = (_Float16)b[r]; }
        } else {
#pragma unroll
            for (int j = 0; j < 8; j++)
                v[j] = (k0 + j < EMB) ? (_Float16)arow[k0 + j] : (_Float16)0.f;
        }
        return v;
    };

    f16x8 av = load_chunk(0);
#pragma unroll
    for (int kc = 0; kc < 10; kc++) {
        *(f16x8*)&lds_a[srow * ASTR + sseg * 8] = av;
        block_sync_lds();
        if (kc < 9) av = load_chunk(kc + 1);
        f16x8 af[4];
#pragma unroll
        for (int mt = 0; mt < 4; mt++)
            af[mt] = *(const f16x8*)&lds_a[(mt * 16 + ln) * ASTR + q * 8];
#pragma unroll
        for (int mt = 0; mt < 4; mt++)
#pragma unroll
            for (int nt = 0; nt < 4; nt++)
                acc[mt][nt] = __builtin_amdgcn_mfma_f32_16x16x32_f16(
                    af[mt], bfrag[kc][nt], acc[mt][nt], 0, 0, 0);
        block_sync_lds();
    }

#pragma unroll
    for (int mt = 0; mt < 4; mt++)
#pragma unroll
        for (int nt = 0; nt < 4; nt++) {
            const int col = wv * 64 + nt * 16 + ln;
#pragma unroll
            for (int r = 0; r < 4; r++) {
                const int mm = m0 + mt * 16 + q * 4 + r;
                if (mm < VOCAB) EW[(long)mm * HID + col] = acc[mt][nt][r];
            }
        }

    __syncthreads();                     // drains vmcnt(0): all block stores done
    if (tid == 0) {
        __threadfence();                 // agent-scope release of EW stores
        __hip_atomic_fetch_add(cnt, 1u, __ATOMIC_RELEASE, __HIP_MEMORY_SCOPE_AGENT);
    }
}

// ---------------------------------------------------------------------------
// Consumer: recurrence. 16 blocks x 16 batch rows, 4 waves split j.
// h ping-pongs in LDS (HSTR=264: conflict-free b128 reads, 2-way-free writes).
// a_t gathered from EmbWi (f32, L3-resident) 2 steps ahead into registers and
// used DIRECTLY as the MFMA accumulator init (no add, no cvt).
// ---------------------------------------------------------------------------
#define HSTR 264
#define HB   (16 * HSTR)
#define WSTR 516   // wtab dword stride: 516%32=4 -> 2-way (free)

__device__ void consumer_body(const float* __restrict__ Wh, const float* __restrict__ EW,
                              const int* __restrict__ words,
                              const float* __restrict__ fcw, const float* __restrict__ fcb,
                              float* __restrict__ out, unsigned int* cnt) {
    __shared__ __attribute__((aligned(16))) _Float16 hbuf[2 * HB];
    __shared__ int wtab[16 * WSTR];
    __shared__ float red[256];

    const int tid  = threadIdx.x;
    const int wv   = tid >> 6;
    const int lane = tid & 63;
    const int ln   = lane & 15;
    const int q    = lane >> 4;
    const int b0   = blockIdx.x * 16;

    // stage words rows for this block's 16 batches (b-major -> contiguous)
    for (int i = tid; i < 16 * S_LEN; i += 256)
        wtab[(i >> 9) * WSTR + (i & 511)] = words[b0 * S_LEN + i];

    // Wh^T fragments: A'[m=j][k] = Wh[k][j], j = wv*64 + mt*16 + ln
    f16x8 whf[8][4];
#pragma unroll
    for (int kc = 0; kc < 8; kc++) {
#pragma unroll
        for (int mt = 0; mt < 4; mt++) {
            const int j = wv * 64 + mt * 16 + ln;
            f16x8 u;
#pragma unroll
            for (int jj = 0; jj < 8; jj++)
                u[jj] = (_Float16)Wh[(kc * 32 + q * 8 + jj) * HID + j];
            whf[kc][mt] = u;
        }
    }

    for (int i = tid; i < 2 * HB; i += 256) hbuf[i] = (_Float16)0.f;
    __syncthreads();

    // wait for the full EmbWi table (any row may be needed at t=0)
    while (__hip_atomic_load(cnt, __ATOMIC_ACQUIRE, __HIP_MEMORY_SCOPE_AGENT) < NPROD)
        __builtin_amdgcn_s_sleep(8);

    const int jbase = wv * 64 + q * 4;   // + mt*16
    f32x4 abuf0[4], abuf1[4];
    {
        const float* r0 = EW + (long)wtab[ln * WSTR + 0] * HID + jbase;
        const float* r1 = EW + (long)wtab[ln * WSTR + 1] * HID + jbase;
#pragma unroll
        for (int mt = 0; mt < 4; mt++) abuf0[mt] = *(const f32x4*)(r0 + mt * 16);
#pragma unroll
        for (int mt = 0; mt < 4; mt++) abuf1[mt] = *(const f32x4*)(r1 + mt * 16);
    }

#define STEP(T, ABUF)                                                                   \
    {                                                                                   \
        const int tt = (T);                                                             \
        const _Float16* hr = hbuf + ((tt & 1) ? HB : 0);                                \
        _Float16*       hw = hbuf + ((tt & 1) ? 0 : HB);                                \
        f16x8 hf[8];                                                                    \
        _Pragma("unroll")                                                               \
        for (int kc = 0; kc < 8; kc++)                                                  \
            hf[kc] = *(const f16x8*)(hr + ln * HSTR + kc * 32 + q * 8);                 \
        f32x4 acc[4];                                                                   \
        _Pragma("unroll")                                                               \
        for (int mt = 0; mt < 4; mt++) acc[mt] = ABUF[mt];  /* preact a_t as C-init */  \
        _Pragma("unroll")                                                               \
        for (int kc = 0; kc < 8; kc++) {                                                \
            _Pragma("unroll")                                                           \
            for (int mt = 0; mt < 4; mt++)                                              \
                acc[mt] = __builtin_amdgcn_mfma_f32_16x16x32_f16(                       \
                    whf[kc][mt], hf[kc], acc[mt], 0, 0, 0);                             \
        }                                                                               \
        const int t2 = (tt + 2 > 511) ? 511 : (tt + 2);                                 \
        const float* rp = EW + (long)wtab[ln * WSTR + t2] * HID + jbase;                \
        _Pragma("unroll")                                                               \
        for (int mt = 0; mt < 4; mt++) ABUF[mt] = *(const f32x4*)(rp + mt * 16);        \
        _Pragma("unroll")                                                               \
        for (int mt = 0; mt < 4; mt++) {                                                \
            f16x4 hp;                                                                   \
            _Pragma("unroll")                                                           \
            for (int r = 0; r < 4; r++) hp[r] = (_Float16)sigmoidf_fast(acc[mt][r]);    \
            *(f16x4*)(hw + ln * HSTR + wv * 64 + mt * 16 + q * 4) = hp;                 \
        }                                                                               \
        block_sync_lds();                                                               \
    }

    for (int t = 0; t < S_LEN; t += 2) {
        STEP(t, abuf0);
        STEP(t + 1, abuf1);
    }
#undef STEP

    const _Float16* hf0 = hbuf;   // step 511 (odd) wrote buffer 0

    {
        const int row = tid >> 4, j0 = (tid & 15) * 16;
        float* dst = out + 256 + (long)(b0 + row) * HID + j0;
#pragma unroll
        for (int v = 0; v < 16; v += 4) {
            f32x4 w;
#pragma unroll
            for (int r = 0; r < 4; r++) w[r] = (float)hf0[row * HSTR + j0 + v + r];
            *(f32x4*)(dst + v) = w;
        }
    }

    {
        const int bl = tid >> 4, part = tid & 15;
        float s = 0.f;
#pragma unroll
        for (int jj = 0; jj < 16; jj++) {
            const int j = part * 16 + jj;
            s += (float)hf0[bl * HSTR + j] * fcw[j];
        }
        red[bl * 16 + part] = s;
    }
    __syncthreads();
    if (tid < 16) {
        float s = fcb[0];
#pragma unroll
        for (int p = 0; p < 16; p++) s += red[tid * 16 + p];
        out[b0 + tid] = sigmoidf_fast(s);
    }
}

// ---------------------------------------------------------------------------
__global__ __launch_bounds__(256, 1)
void k_fused(const int* __restrict__ words, const float* __restrict__ emb,
             const float* __restrict__ Wi, const float* __restrict__ Wh,
             const float* __restrict__ fcw, const float* __restrict__ fcb,
             float* __restrict__ EW, unsigned int* cnt, float* __restrict__ out) {
    if (blockIdx.x < 16) consumer_body(Wh, EW, words, fcw, fcb, out, cnt);
    else                 producer_body(blockIdx.x - 16, emb, Wi, EW, cnt);
}

__global__ void k_init(unsigned int* cnt) {
    if (threadIdx.x == 0) *cnt = 0u;
}

extern "C" void kernel_launch(void* const* d_in, const int* in_sizes, int n_in,
                              void* d_out, int out_size, void* d_ws, size_t ws_size,
                              hipStream_t stream) {
    const int*   words = (const int*)d_in[0];
    const float* emb   = (const float*)d_in[1];
    const float* Wi    = (const float*)d_in[2];
    const float* Wh    = (const float*)d_in[3];
    const float* fcw   = (const float*)d_in[4];
    const float* fcb   = (const float*)d_in[5];
    float*        EW   = (float*)d_ws;                       // 51.5 MB, f32
    unsigned int* cnt  = (unsigned int*)((char*)d_ws + EMBWI_BYTES);
    float*        outp = (float*)d_out;

    hipLaunchKernelGGL(k_init, dim3(1), dim3(64), 0, stream, cnt);
    hipLaunchKernelGGL(k_fused, dim3(16 + NPROD), dim3(256), 0, stream,
                       words, emb, Wi, Wh, fcw, fcb, EW, cnt, outp);
}